// Round 2
// baseline (916.042 us; speedup 1.0000x reference)
//
#include <hip/hip_runtime.h>

// ---------------------------------------------------------------------------
// NAMTuring forward, MI355X.  Pipeline:
//  K0 convert -> K1 input GEMMs (bf16 MFMA) -> K2 biLSTM scan (MFMA+f32 state)
//  -> K3 action head (softmax/sigmoid) -> K4 position scan -> K5 tape scan
//  (tape in registers) -> K6 output GEMM.
// S=256 B=64 IN=128 HID=128 NT=2 DIM=64 LH=64 TAPELEN=128
// ---------------------------------------------------------------------------

typedef unsigned short u16;
typedef __attribute__((ext_vector_type(8))) __bf16 bf16x8;
typedef __attribute__((ext_vector_type(4))) float f32x4;

__device__ __forceinline__ u16 f2bf(float x) {
  unsigned u = __builtin_bit_cast(unsigned, x);
  u += 0x7fffu + ((u >> 16) & 1u);
  return (u16)(u >> 16);
}
__device__ __forceinline__ float sigm_f(float x) { return 1.f / (1.f + __expf(-x)); }
__device__ __forceinline__ float tanh_f(float x) { return 1.f - 2.f / (__expf(2.f * x) + 1.f); }

// ---------------- K0: f32 -> bf16 conversions (one launch) -----------------
struct ConvArgs {
  const float* src[7];
  u16* dst[7];
  int off[8];
};

__global__ __launch_bounds__(256) void k_convert(ConvArgs a) {
  int total = a.off[7];
  for (int i = blockIdx.x * 256 + threadIdx.x; i < total; i += gridDim.x * 256) {
    int s = 0;
#pragma unroll
    for (int k = 1; k < 7; ++k) s += (i >= a.off[k]);
    int j = i - a.off[s];
    a.dst[s][j] = f2bf(a.src[s][j]);
  }
}

// ------------- per-wave 16x16 MFMA tile, C = A @ W^T + bias, K=128 ----------
__device__ __forceinline__ void gemm_tile(const u16* A, const u16* W,
                                          const float* b1, const float* b2,
                                          float* C, int mt, int nt, int N, int lane) {
  const int rc = lane & 15;       // A: M-row ; W: N-col (same lane formula)
  const int kq = lane >> 4;
  f32x4 acc = {0.f, 0.f, 0.f, 0.f};
#pragma unroll
  for (int kc = 0; kc < 4; ++kc) {
    bf16x8 av = *(const bf16x8*)(A + (size_t)(mt * 16 + rc) * 128 + kc * 32 + kq * 8);
    bf16x8 wv = *(const bf16x8*)(W + (size_t)(nt * 16 + rc) * 128 + kc * 32 + kq * 8);
    acc = __builtin_amdgcn_mfma_f32_16x16x32_bf16(av, wv, acc, 0, 0, 0);
  }
  const int n = nt * 16 + rc;
  float bias = b1[n] + (b2 ? b2[n] : 0.f);
  const int m0 = mt * 16 + kq * 4;
#pragma unroll
  for (int j = 0; j < 4; ++j) C[(size_t)(m0 + j) * N + n] = acc[j] + bias;
}

// ---------------- K1: xproj_f, xproj_r, values in one launch ----------------
__global__ __launch_bounds__(256) void k_gemm_in(
    const u16* Abf, const u16* Wf, const u16* Wr, const u16* Wv,
    const float* bihf, const float* bhhf, const float* bihr, const float* bhhr,
    const float* bval, float* xf, float* xr, float* val) {
  int lane = threadIdx.x & 63;
  int wid = blockIdx.x * 4 + (threadIdx.x >> 6);   // 0..40959
  if (wid < 16384) {
    gemm_tile(Abf, Wf, bihf, bhhf, xf, wid >> 4, wid & 15, 256, lane);
  } else if (wid < 32768) {
    int w2 = wid - 16384;
    gemm_tile(Abf, Wr, bihr, bhhr, xr, w2 >> 4, w2 & 15, 256, lane);
  } else {
    int w2 = wid - 32768;
    gemm_tile(Abf, Wv, bval, nullptr, val, w2 >> 3, w2 & 7, 128, lane);
  }
}

// ---------------- K6: outputs = readouts @ W_out^T + b_out ------------------
__global__ __launch_bounds__(256) void k_gemm_out(const u16* A, const u16* W,
                                                  const float* b1, float* C) {
  int lane = threadIdx.x & 63;
  int wid = blockIdx.x * 4 + (threadIdx.x >> 6);   // 0..8191
  gemm_tile(A, W, b1, nullptr, C, wid >> 3, wid & 7, 128, lane);
}

// ---------------- K2: bidirectional LSTM scan -------------------------------
// grid = 16 blocks: blockIdx = dir + 2*chunk, chunk covers 8 batch rows.
// G[16(batch,pad8) x 256(gates)] = h @ Whh^T + xproj ; MFMA 16x16x32 bf16.
// Wave w owns gate columns [64w,64w+64) -> gate type == w (i,f,g,o).
__global__ __launch_bounds__(256) void k_lstm(
    const u16* Whhf, const u16* Whhr, const float* xpf, const float* xpr,
    float* hidden /* f32 [S][B][128] */) {
  const int tid = threadIdx.x;
  const int lane = tid & 63;
  const int w = __builtin_amdgcn_readfirstlane(tid >> 6);
  const int dir = blockIdx.x & 1;
  const int b_base = (blockIdx.x >> 1) * 8;
  const u16* Whh = dir ? Whhr : Whhf;
  const float* xp = dir ? xpr : xpf;

  __shared__ u16 h_lds[1024];        // [16][64] bf16, XOR-swizzled
  __shared__ float G_lds[16][258];   // post-nonlin gates, padded

  for (int i = tid; i < 1024; i += 256) h_lds[i] = 0;
  __syncthreads();

  const int col = lane & 15;
  const int kq = lane >> 4;

  // Preload Whh fragments for this wave's 4 col-tiles x 2 k-chunks.
  bf16x8 wf[4][2];
#pragma unroll
  for (int nt = 0; nt < 4; ++nt)
#pragma unroll
    for (int kc = 0; kc < 2; ++kc)
      wf[nt][kc] = *(const bf16x8*)(Whh + (size_t)(w * 64 + nt * 16 + col) * 64 + kc * 32 + kq * 8);

  // c/h state: thread owns (b_loc, hid0) and (b_loc, hid0+1)
  const int b_loc = tid >> 5;            // 0..7
  const int hid0 = (tid & 31) * 2;       // even
  float c0 = 0.f, c1 = 0.f;

  float xc[16], xn[16];
  {
    int s0 = dir ? 255 : 0;
#pragma unroll
    for (int nt = 0; nt < 4; ++nt)
#pragma unroll
      for (int j = 0; j < 4; ++j) {
        int r = kq * 4 + j;
        xc[nt * 4 + j] = (r < 8)
            ? xp[((size_t)s0 * 64 + b_base + r) * 256 + w * 64 + nt * 16 + col]
            : 0.f;
      }
  }

  for (int it = 0; it < 256; ++it) {
    const int s = dir ? (255 - it) : it;
    // A fragments from swizzled h_lds
    bf16x8 af[2];
#pragma unroll
    for (int kc = 0; kc < 2; ++kc) {
      unsigned off = ((unsigned)(col * 128 + kc * 64 + kq * 16)) ^ ((unsigned)(col & 7) << 4);
      af[kc] = *(const bf16x8*)((const char*)h_lds + off);
    }
    f32x4 acc[4];
#pragma unroll
    for (int nt = 0; nt < 4; ++nt) {
      f32x4 t;
      t[0] = xc[nt * 4 + 0]; t[1] = xc[nt * 4 + 1];
      t[2] = xc[nt * 4 + 2]; t[3] = xc[nt * 4 + 3];
      acc[nt] = t;
    }
#pragma unroll
    for (int kc = 0; kc < 2; ++kc)
#pragma unroll
      for (int nt = 0; nt < 4; ++nt)
        acc[nt] = __builtin_amdgcn_mfma_f32_16x16x32_bf16(af[kc], wf[nt][kc], acc[nt], 0, 0, 0);

    // prefetch next step's xproj while MFMA/nonlin run
    if (it + 1 < 256) {
      int sn = dir ? (s - 1) : (s + 1);
#pragma unroll
      for (int nt = 0; nt < 4; ++nt)
#pragma unroll
        for (int j = 0; j < 4; ++j) {
          int r = kq * 4 + j;
          xn[nt * 4 + j] = (r < 8)
              ? xp[((size_t)sn * 64 + b_base + r) * 256 + w * 64 + nt * 16 + col]
              : 0.f;
        }
    }

    // nonlinearity + write gates (only valid batch rows: lanes 0..31)
    if (lane < 32) {
#pragma unroll
      for (int nt = 0; nt < 4; ++nt)
#pragma unroll
        for (int j = 0; j < 4; ++j) {
          float gv = acc[nt][j];
          float a = (w == 2) ? tanh_f(gv) : sigm_f(gv);
          G_lds[kq * 4 + j][w * 64 + nt * 16 + col] = a;
        }
    }
    __syncthreads();

    // c/h update (all 256 threads, 2 pairs each)
    {
      const float* Gr = &G_lds[b_loc][0];
      float gi0 = Gr[hid0], gi1 = Gr[hid0 + 1];
      float gf0 = Gr[64 + hid0], gf1 = Gr[64 + hid0 + 1];
      float gg0 = Gr[128 + hid0], gg1 = Gr[128 + hid0 + 1];
      float go0 = Gr[192 + hid0], go1 = Gr[192 + hid0 + 1];
      c0 = gf0 * c0 + gi0 * gg0;
      c1 = gf1 * c1 + gi1 * gg1;
      float h0 = go0 * tanh_f(c0);
      float h1 = go1 * tanh_f(c1);
      unsigned u = (unsigned)f2bf(h0) | ((unsigned)f2bf(h1) << 16);
      unsigned off = ((unsigned)(b_loc * 128 + hid0 * 2)) ^ ((unsigned)(b_loc & 7) << 4);
      *(unsigned*)((char*)h_lds + off) = u;
      size_t hb = ((size_t)s * 64 + b_base + b_loc) * 128 + dir * 64 + hid0;
      hidden[hb] = h0;
      hidden[hb + 1] = h1;
    }
    __syncthreads();

#pragma unroll
    for (int q = 0; q < 16; ++q) xc[q] = xn[q];
  }
}

// ---------------- K3: actions + softmax/sigmoid -----------------------------
// thread = (s*B+b, t); act[s][b][t][8] = {rdir0..2, wdir0..2, rw0, rw1}
__global__ __launch_bounds__(256) void k_act(const float* hidden, const float* W_act,
                                             const float* b_act, float* act) {
  __shared__ float Wl[16][129];
  __shared__ float bl[16];
  int tid = threadIdx.x;
  for (int i = tid; i < 2048; i += 256) Wl[i >> 7][i & 127] = W_act[i];
  if (tid < 16) bl[tid] = b_act[tid];
  __syncthreads();
  int idx = blockIdx.x * 256 + tid;     // < 32768
  int t = idx & 1, sb = idx >> 1;
  const float* hr = hidden + (size_t)sb * 128;
  float dot[8] = {0, 0, 0, 0, 0, 0, 0, 0};
#pragma unroll 4
  for (int k = 0; k < 128; k += 4) {
    float4 hv = *(const float4*)(hr + k);
#pragma unroll
    for (int j = 0; j < 8; ++j) {
      dot[j] += hv.x * Wl[t * 8 + j][k] + hv.y * Wl[t * 8 + j][k + 1] +
                hv.z * Wl[t * 8 + j][k + 2] + hv.w * Wl[t * 8 + j][k + 3];
    }
  }
#pragma unroll
  for (int j = 0; j < 8; ++j) dot[j] += bl[t * 8 + j];
  // softmax over 0..2 (read dir) and 3..5 (write dir), sigmoid 6,7
  float m1 = fmaxf(fmaxf(dot[0], dot[1]), dot[2]);
  float e0 = __expf(dot[0] - m1), e1 = __expf(dot[1] - m1), e2 = __expf(dot[2] - m1);
  float i1 = 1.f / (e0 + e1 + e2);
  float m2 = fmaxf(fmaxf(dot[3], dot[4]), dot[5]);
  float f0 = __expf(dot[3] - m2), f1 = __expf(dot[4] - m2), f2 = __expf(dot[5] - m2);
  float i2 = 1.f / (f0 + f1 + f2);
  float rw0 = sigm_f(dot[6]), rw1 = sigm_f(dot[7]);
  float4* o = (float4*)(act + (size_t)idx * 8);
  o[0] = make_float4(e0 * i1, e1 * i1, e2 * i1, f0 * i2);
  o[1] = make_float4(f1 * i2, f2 * i2, rw0, rw1);
}

// ---------------- K4: position scan (128 chains) ----------------------------
// Writes per-step coefficients: wcoef = bf16(wpos), rcoef = bf16(rpos*rw0),
// rw1arr = f32 rw1.  NOTE faithful-to-ref: BOTH pos updates roll rpos.
__global__ __launch_bounds__(128) void k_pos(const float* act, u16* wcoef, u16* rcoef,
                                             float* rw1arr, float* out_rpos, float* out_wpos) {
  const int bt = blockIdx.x;   // b = bt>>1, t = bt&1
  const int l = threadIdx.x;
  __shared__ float rbuf[128];
  float rp = (l == 0) ? 1.f : 0.f;
  float wp = rp;
  const float* abase = act + (size_t)bt * 8;
  float4 a0 = *(const float4*)(abase);
  float4 a1 = *(const float4*)(abase + 4);
  for (int s = 0; s < 256; ++s) {
    float rd0 = a0.x, rd1 = a0.y, rd2 = a0.z;
    float wd0 = a0.w, wd1 = a1.x, wd2 = a1.y;
    float rw0 = a1.z, rw1 = a1.w;
    if (s + 1 < 256) {
      const float* an = abase + (size_t)(s + 1) * 1024;
      a0 = *(const float4*)an;
      a1 = *(const float4*)(an + 4);
    }
    size_t ci = ((size_t)s * 128 + bt) * 128 + l;
    wcoef[ci] = f2bf(wp);
    rcoef[ci] = f2bf(rp * rw0);
    if (l == 0) rw1arr[s * 128 + bt] = rw1;
    rbuf[l] = rp;
    __syncthreads();
    float rpp = rbuf[(l + 1) & 127];
    float rpm = rbuf[(l + 127) & 127];
    __syncthreads();
    wp = rpp * wd0 + wp * wd1 + rpm * wd2;   // rolls of rpos (faithful)
    rp = rpp * rd0 + rp * rd1 + rpm * rd2;
  }
  int b = bt >> 1, t = bt & 1;
  out_rpos[(size_t)(l * 64 + b) * 2 + t] = rp;
  out_wpos[(size_t)(l * 64 + b) * 2 + t] = wp;
}

// ---------------- K5: tape scan, tape in registers --------------------------
// 128 blocks (b,t) x 256 thr (4 waves). Wave g owns tape rows [32g,32g+32),
// lane owns column c. Coefficients are wave-uniform -> scalar loads, bf16.
__global__ __launch_bounds__(256) void k_tape(
    const float* values, const u16* wcoef, const u16* rcoef, const float* rw1arr,
    u16* readouts, float* out_tape) {
  const int bt = blockIdx.x;
  const int b = bt >> 1, t = bt & 1;
  const int tid = threadIdx.x;
  const int c = tid & 63;
  const int g = __builtin_amdgcn_readfirstlane(tid >> 6);
  __shared__ float lds_po[256], lds_pr[256];
  float tape[32];
#pragma unroll
  for (int j = 0; j < 32; ++j) tape[j] = 0.f;

  const unsigned* wcu = (const unsigned*)wcoef;
  const unsigned* rcu = (const unsigned*)rcoef;
  unsigned wc[16], rc[16], wn[16], rn[16];
  float rw1c, rw1n, vc, vn;
  {
    size_t base = (size_t)bt * 64 + g * 16;
#pragma unroll
    for (int q = 0; q < 16; ++q) { wc[q] = wcu[base + q]; rc[q] = rcu[base + q]; }
    rw1c = rw1arr[bt];
    vc = values[(size_t)b * 128 + t * 64 + c];
  }
  for (int s = 0; s < 256; ++s) {
    if (s + 1 < 256) {
      size_t base = ((size_t)(s + 1) * 128 + bt) * 64 + g * 16;
#pragma unroll
      for (int q = 0; q < 16; ++q) { wn[q] = wcu[base + q]; rn[q] = rcu[base + q]; }
      rw1n = rw1arr[(size_t)(s + 1) * 128 + bt];
      vn = values[((size_t)(s + 1) * 64 + b) * 128 + t * 64 + c];
    }
    float po = 0.f;
#pragma unroll
    for (int q = 0; q < 16; ++q) {
      float w0 = __builtin_bit_cast(float, wc[q] << 16);
      float w1 = __builtin_bit_cast(float, wc[q] & 0xffff0000u);
      po += tape[2 * q] * w0;
      po += tape[2 * q + 1] * w1;
    }
    lds_po[(g << 6) + c] = po;
    __syncthreads();
    float oldv = lds_po[c] + lds_po[64 + c] + lds_po[128 + c] + lds_po[192 + c];
    float dscale = rw1c * (vc - oldv);
    float pr = 0.f;
#pragma unroll
    for (int q = 0; q < 16; ++q) {
      float w0 = __builtin_bit_cast(float, wc[q] << 16);
      float w1 = __builtin_bit_cast(float, wc[q] & 0xffff0000u);
      float r0 = __builtin_bit_cast(float, rc[q] << 16);
      float r1 = __builtin_bit_cast(float, rc[q] & 0xffff0000u);
      tape[2 * q] += w0 * dscale;
      pr += tape[2 * q] * r0;
      tape[2 * q + 1] += w1 * dscale;
      pr += tape[2 * q + 1] * r1;
    }
    lds_pr[(g << 6) + c] = pr;
    __syncthreads();
    if (g == 0) {
      float ro = lds_pr[c] + lds_pr[64 + c] + lds_pr[128 + c] + lds_pr[192 + c];
      readouts[((size_t)s * 64 + b) * 128 + t * 64 + c] = f2bf(ro);
    }
#pragma unroll
    for (int q = 0; q < 16; ++q) { wc[q] = wn[q]; rc[q] = rn[q]; }
    rw1c = rw1n;
    vc = vn;
  }
#pragma unroll
  for (int j = 0; j < 32; ++j) {
    int l = (g << 5) + j;
    out_tape[((size_t)(l * 64 + b) * 2 + t) * 64 + c] = tape[j];
  }
}

// ---------------------------------------------------------------------------
extern "C" void kernel_launch(void* const* d_in, const int* in_sizes, int n_in,
                              void* d_out, int out_size, void* d_ws, size_t ws_size,
                              hipStream_t stream) {
  const float* inputs = (const float*)d_in[0];
  const float* W_ih_f = (const float*)d_in[2];
  const float* W_hh_f = (const float*)d_in[3];
  const float* b_ih_f = (const float*)d_in[4];
  const float* b_hh_f = (const float*)d_in[5];
  const float* W_ih_r = (const float*)d_in[6];
  const float* W_hh_r = (const float*)d_in[7];
  const float* b_ih_r = (const float*)d_in[8];
  const float* b_hh_r = (const float*)d_in[9];
  const float* W_act  = (const float*)d_in[10];
  const float* b_act  = (const float*)d_in[11];
  const float* W_val  = (const float*)d_in[12];
  const float* b_val  = (const float*)d_in[13];
  const float* W_out  = (const float*)d_in[14];
  const float* b_out  = (const float*)d_in[15];

  char* ws = (char*)d_ws;
  u16* in_bf    = (u16*)(ws + 0);
  u16* wihf_bf  = (u16*)(ws + 4194304);
  u16* whhf_bf  = (u16*)(ws + 4259840);
  u16* wihr_bf  = (u16*)(ws + 4292608);
  u16* whhr_bf  = (u16*)(ws + 4358144);
  u16* wval_bf  = (u16*)(ws + 4390912);
  u16* wout_bf  = (u16*)(ws + 4423680);
  float* xf     = (float*)(ws + 4456448);
  float* xr     = (float*)(ws + 21233664);
  float* values = (float*)(ws + 38010880);
  float* hidden = (float*)(ws + 46399488);
  float* act    = (float*)(ws + 54788096);
  // overlays (xf/xr dead after k_lstm). Sizes: wcoef/rcoef 8388608 B each,
  // rw1arr 131072 B, readouts 4194304 B -> [4456448, 25559040) < 38010880 OK.
  u16* wcoef    = (u16*)(ws + 4456448);
  u16* rcoef    = (u16*)(ws + 12845056);
  float* rw1arr = (float*)(ws + 21233664);
  u16* readouts = (u16*)(ws + 21364736);

  float* out_outputs = (float*)d_out;
  float* out_tape = out_outputs + 2097152;
  float* out_rpos = out_outputs + 3145728;
  float* out_wpos = out_outputs + 3162112;

  ConvArgs ca;
  ca.src[0] = inputs; ca.dst[0] = in_bf;
  ca.src[1] = W_ih_f; ca.dst[1] = wihf_bf;
  ca.src[2] = W_hh_f; ca.dst[2] = whhf_bf;
  ca.src[3] = W_ih_r; ca.dst[3] = wihr_bf;
  ca.src[4] = W_hh_r; ca.dst[4] = whhr_bf;
  ca.src[5] = W_val;  ca.dst[5] = wval_bf;
  ca.src[6] = W_out;  ca.dst[6] = wout_bf;
  const int offs[8] = {0, 2097152, 2129920, 2146304, 2179072, 2195456, 2211840, 2228224};
  for (int i = 0; i < 8; ++i) ca.off[i] = offs[i];

  hipLaunchKernelGGL(k_convert, dim3(4352), dim3(256), 0, stream, ca);
  hipLaunchKernelGGL(k_gemm_in, dim3(10240), dim3(256), 0, stream,
                     in_bf, wihf_bf, wihr_bf, wval_bf,
                     b_ih_f, b_hh_f, b_ih_r, b_hh_r, b_val, xf, xr, values);
  hipLaunchKernelGGL(k_lstm, dim3(16), dim3(256), 0, stream,
                     whhf_bf, whhr_bf, xf, xr, hidden);
  hipLaunchKernelGGL(k_act, dim3(128), dim3(256), 0, stream, hidden, W_act, b_act, act);
  hipLaunchKernelGGL(k_pos, dim3(128), dim3(128), 0, stream,
                     act, wcoef, rcoef, rw1arr, out_rpos, out_wpos);
  hipLaunchKernelGGL(k_tape, dim3(128), dim3(256), 0, stream,
                     values, wcoef, rcoef, rw1arr, readouts, out_tape);
  hipLaunchKernelGGL(k_gemm_out, dim3(2048), dim3(256), 0, stream,
                     readouts, wout_bf, b_out, out_outputs);
}

// Round 3
// 655.268 us; speedup vs baseline: 1.3980x; 1.3980x over previous
//
#include <hip/hip_runtime.h>

// ---------------------------------------------------------------------------
// NAMTuring forward, MI355X.
//  K0 convert -> K1 input GEMMs -> K2 biLSTM scan (fused gates, 1 barrier/step)
//  -> K3a action GEMM (MFMA) -> K3b softmax -> K4 pos scan (1 wave, shfl)
//  -> K5 tape scan (regs, 1 barrier/step) -> K6 output GEMM.
// S=256 B=64 IN=128 HID=128 NT=2 DIM=64 LH=64 TAPELEN=128
// ---------------------------------------------------------------------------

typedef unsigned short u16;
typedef __attribute__((ext_vector_type(8))) __bf16 bf16x8;
typedef __attribute__((ext_vector_type(4))) float f32x4;

__device__ __forceinline__ u16 f2bf(float x) {
  unsigned u = __builtin_bit_cast(unsigned, x);
  u += 0x7fffu + ((u >> 16) & 1u);
  return (u16)(u >> 16);
}
__device__ __forceinline__ float sigm_f(float x) { return 1.f / (1.f + __expf(-x)); }
__device__ __forceinline__ float tanh_f(float x) { return 1.f - 2.f / (__expf(2.f * x) + 1.f); }

// ---------------- K0: f32 -> bf16 conversions (one launch) -----------------
struct ConvArgs {
  const float* src[8];
  u16* dst[8];
  int off[9];
};

__global__ __launch_bounds__(256) void k_convert(ConvArgs a) {
  int total = a.off[8];
  for (int i = blockIdx.x * 256 + threadIdx.x; i < total; i += gridDim.x * 256) {
    int s = 0;
#pragma unroll
    for (int k = 1; k < 8; ++k) s += (i >= a.off[k]);
    int j = i - a.off[s];
    a.dst[s][j] = f2bf(a.src[s][j]);
  }
}

// ------------- per-wave 16x16 MFMA tile, C = A @ W^T + bias, K=128 ----------
__device__ __forceinline__ void gemm_tile(const u16* A, const u16* W,
                                          const float* b1, const float* b2,
                                          float* C, int mt, int nt, int N, int lane) {
  const int rc = lane & 15;
  const int kq = lane >> 4;
  f32x4 acc = {0.f, 0.f, 0.f, 0.f};
#pragma unroll
  for (int kc = 0; kc < 4; ++kc) {
    bf16x8 av = *(const bf16x8*)(A + (size_t)(mt * 16 + rc) * 128 + kc * 32 + kq * 8);
    bf16x8 wv = *(const bf16x8*)(W + (size_t)(nt * 16 + rc) * 128 + kc * 32 + kq * 8);
    acc = __builtin_amdgcn_mfma_f32_16x16x32_bf16(av, wv, acc, 0, 0, 0);
  }
  const int n = nt * 16 + rc;
  float bias = b1[n] + (b2 ? b2[n] : 0.f);
  const int m0 = mt * 16 + kq * 4;
#pragma unroll
  for (int j = 0; j < 4; ++j) C[(size_t)(m0 + j) * N + n] = acc[j] + bias;
}

// ---------------- K1: xproj_f, xproj_r, values in one launch ----------------
__global__ __launch_bounds__(256) void k_gemm_in(
    const u16* Abf, const u16* Wf, const u16* Wr, const u16* Wv,
    const float* bihf, const float* bhhf, const float* bihr, const float* bhhr,
    const float* bval, float* xf, float* xr, float* val) {
  int lane = threadIdx.x & 63;
  int wid = blockIdx.x * 4 + (threadIdx.x >> 6);   // 0..40959
  if (wid < 16384) {
    gemm_tile(Abf, Wf, bihf, bhhf, xf, wid >> 4, wid & 15, 256, lane);
  } else if (wid < 32768) {
    int w2 = wid - 16384;
    gemm_tile(Abf, Wr, bihr, bhhr, xr, w2 >> 4, w2 & 15, 256, lane);
  } else {
    int w2 = wid - 32768;
    gemm_tile(Abf, Wv, bval, nullptr, val, w2 >> 3, w2 & 7, 128, lane);
  }
}

// ---------------- K3a: action pre-act GEMM: hidden_bf @ W_act^T + b ---------
__global__ __launch_bounds__(256) void k_gemm_act(const u16* A, const u16* W,
                                                  const float* b1, float* C) {
  int lane = threadIdx.x & 63;
  int wid = blockIdx.x * 4 + (threadIdx.x >> 6);   // 0..2047 (M-tiles), N=16
  gemm_tile(A, W, b1, nullptr, C, wid, 0, 16, lane);
}

// ---------------- K6: outputs = readouts @ W_out^T + b_out ------------------
__global__ __launch_bounds__(256) void k_gemm_out(const u16* A, const u16* W,
                                                  const float* b1, float* C) {
  int lane = threadIdx.x & 63;
  int wid = blockIdx.x * 4 + (threadIdx.x >> 6);   // 0..8191
  gemm_tile(A, W, b1, nullptr, C, wid >> 3, wid & 7, 128, lane);
}

// ---------------- K2: bidirectional LSTM scan (fused gate layout) -----------
// grid = 8 blocks: blockIdx = dir + 2*chunk, chunk = 16 batch rows.
// Wave v owns gate col-slice [16v,16v+16) of EACH gate: tiles {v,4+v,8+v,12+v}.
// After MFMA, each thread holds i,f,g,o for (4 batch rows x 1 col) locally:
// c/h update in registers, no gate LDS. One barrier/step (dbuf h_lds).
// xproj prefetch distance 2 via x0/x1 ping-pong (no rotation movs).
__global__ __launch_bounds__(256) void k_lstm(
    const u16* Whhf, const u16* Whhr, const float* xpf, const float* xpr,
    u16* hidden_bf /* [S][B][128] bf16 */) {
  const int tid = threadIdx.x;
  const int lane = tid & 63;
  const int v = __builtin_amdgcn_readfirstlane(tid >> 6);
  const int dir = blockIdx.x & 1;
  const int b_base = (blockIdx.x >> 1) * 16;
  const u16* Whh = dir ? Whhr : Whhf;
  const float* xp = dir ? xpr : xpf;

  __shared__ u16 h_lds[2][1024];   // [buf][16 rows][64 cols] bf16, XOR-swizzled
  for (int i = tid; i < 1024; i += 256) h_lds[0][i] = 0;

  const int cl = lane & 15;
  const int kq = lane >> 4;
  const int nbase = v * 16 + cl;       // gate col within 64-block
  const int rbase = b_base + kq * 4;   // global batch row base for this thread

  // Whh fragments: B-frag rows = gate index gt*64 + nbase, k over 64.
  bf16x8 wf[4][2];
#pragma unroll
  for (int gt = 0; gt < 4; ++gt)
#pragma unroll
    for (int kc = 0; kc < 2; ++kc)
      wf[gt][kc] = *(const bf16x8*)(Whh + (size_t)(gt * 64 + nbase) * 64 + kc * 32 + kq * 8);

  float c4[4] = {0.f, 0.f, 0.f, 0.f};
  float x0[16], x1[16];

#define LOADX(dst, ss)                                                       \
  _Pragma("unroll") for (int gt = 0; gt < 4; ++gt)                           \
  _Pragma("unroll") for (int j = 0; j < 4; ++j)                              \
    dst[gt * 4 + j] = xp[((size_t)(ss)*64 + rbase + j) * 256 + gt * 64 + nbase];

  { int s0 = dir ? 255 : 0; LOADX(x0, s0); }
  { int s1 = dir ? 254 : 1; LOADX(x1, s1); }

#define LSTM_STEP(XB, IT)                                                     \
  {                                                                           \
    const int it_ = (IT);                                                     \
    const int s_ = dir ? (255 - it_) : it_;                                   \
    __syncthreads();                                                          \
    bf16x8 af[2];                                                             \
    _Pragma("unroll") for (int kc = 0; kc < 2; ++kc) {                        \
      unsigned off = ((unsigned)(cl * 128 + kc * 64 + kq * 16)) ^             \
                     ((unsigned)(cl & 7) << 4);                               \
      af[kc] = *(const bf16x8*)((const char*)h_lds[it_ & 1] + off);           \
    }                                                                         \
    f32x4 acc[4];                                                             \
    _Pragma("unroll") for (int gt = 0; gt < 4; ++gt) {                        \
      f32x4 t_;                                                               \
      t_[0] = XB[gt * 4 + 0]; t_[1] = XB[gt * 4 + 1];                         \
      t_[2] = XB[gt * 4 + 2]; t_[3] = XB[gt * 4 + 3];                         \
      acc[gt] = t_;                                                           \
    }                                                                         \
    if (it_ + 2 < 256) { int sp_ = dir ? (253 - it_) : (it_ + 2); LOADX(XB, sp_); } \
    _Pragma("unroll") for (int kc = 0; kc < 2; ++kc)                          \
    _Pragma("unroll") for (int gt = 0; gt < 4; ++gt)                          \
      acc[gt] = __builtin_amdgcn_mfma_f32_16x16x32_bf16(af[kc], wf[gt][kc],   \
                                                        acc[gt], 0, 0, 0);    \
    u16* hw = h_lds[(it_ + 1) & 1];                                           \
    _Pragma("unroll") for (int j = 0; j < 4; ++j) {                           \
      float gi = sigm_f(acc[0][j]);                                           \
      float gf = sigm_f(acc[1][j]);                                           \
      float gg = tanh_f(acc[2][j]);                                           \
      float go = sigm_f(acc[3][j]);                                           \
      float cc = gf * c4[j] + gi * gg;                                        \
      c4[j] = cc;                                                             \
      float h_ = go * tanh_f(cc);                                             \
      u16 hv = f2bf(h_);                                                      \
      int row = kq * 4 + j;                                                   \
      unsigned off = ((unsigned)(row * 128 + nbase * 2)) ^                    \
                     ((unsigned)(row & 7) << 4);                              \
      *(u16*)((char*)hw + off) = hv;                                          \
      hidden_bf[((size_t)s_ * 64 + b_base + row) * 128 + dir * 64 + nbase] = hv; \
    }                                                                         \
  }

  for (int it2 = 0; it2 < 256; it2 += 2) {
    LSTM_STEP(x0, it2);
    LSTM_STEP(x1, it2 + 1);
  }
#undef LSTM_STEP
#undef LOADX
}

// ---------------- K3b: softmax/sigmoid on pre-activations -------------------
__global__ __launch_bounds__(256) void k_actsm(const float* raw, float* act) {
  int idx = blockIdx.x * 256 + threadIdx.x;   // 32768 = (s*B+b, t)
  const float* r = raw + (size_t)idx * 8;
  float4 d0 = *(const float4*)r;
  float4 d1 = *(const float4*)(r + 4);
  float m1 = fmaxf(fmaxf(d0.x, d0.y), d0.z);
  float e0 = __expf(d0.x - m1), e1 = __expf(d0.y - m1), e2 = __expf(d0.z - m1);
  float i1 = 1.f / (e0 + e1 + e2);
  float m2 = fmaxf(fmaxf(d0.w, d1.x), d1.y);
  float f0 = __expf(d0.w - m2), f1 = __expf(d1.x - m2), f2 = __expf(d1.y - m2);
  float i2 = 1.f / (f0 + f1 + f2);
  float rw0 = sigm_f(d1.z), rw1 = sigm_f(d1.w);
  float4* o = (float4*)(act + (size_t)idx * 8);
  o[0] = make_float4(e0 * i1, e1 * i1, e2 * i1, f0 * i2);
  o[1] = make_float4(f1 * i2, f2 * i2, rw0, rw1);
}

// ---------------- K4: position scan — 1 wave per (b,t) chain ----------------
// lane l holds slots (2l, 2l+1); rolls via 2 __shfl, no LDS/barriers.
__global__ __launch_bounds__(64) void k_pos(const float* act, u16* wcoef, u16* rcoef,
                                            float* rw1arr, float* out_rpos, float* out_wpos) {
  const int bt = blockIdx.x;
  const int l = threadIdx.x;
  float rpe = (l == 0) ? 1.f : 0.f, rpo = 0.f;
  float wpe = rpe, wpo = 0.f;
  const float* abase = act + (size_t)bt * 8;
  float4 a0 = *(const float4*)abase;
  float4 a1 = *(const float4*)(abase + 4);
  unsigned* wcu = (unsigned*)wcoef;
  unsigned* rcu = (unsigned*)rcoef;
  for (int s = 0; s < 256; ++s) {
    float rd0 = a0.x, rd1 = a0.y, rd2 = a0.z;
    float wd0 = a0.w, wd1 = a1.x, wd2 = a1.y;
    float rw0 = a1.z, rw1 = a1.w;
    if (s + 1 < 256) {
      const float* an = abase + (size_t)(s + 1) * 1024;
      a0 = *(const float4*)an;
      a1 = *(const float4*)(an + 4);
    }
    size_t ci = ((size_t)s * 128 + bt) * 64 + l;
    wcu[ci] = (unsigned)f2bf(wpe) | ((unsigned)f2bf(wpo) << 16);
    rcu[ci] = (unsigned)f2bf(rpe * rw0) | ((unsigned)f2bf(rpo * rw0) << 16);
    if (l == 0) rw1arr[s * 128 + bt] = rw1;
    float up_odd = __shfl(rpo, (l + 63) & 63);   // rp[2l-1] (wraps)
    float dn_even = __shfl(rpe, (l + 1) & 63);   // rp[2l+2] (wraps)
    float n_e = up_odd, n_o = rpe;    // roll(rpos,+1)
    float p_e = rpo, p_o = dn_even;   // roll(rpos,-1)
    wpe = p_e * wd0 + wpe * wd1 + n_e * wd2;
    wpo = p_o * wd0 + wpo * wd1 + n_o * wd2;
    rpe = p_e * rd0 + rpe * rd1 + n_e * rd2;
    rpo = p_o * rd0 + rpo * rd1 + n_o * rd2;
  }
  int b = bt >> 1, tt = bt & 1;
  out_rpos[((size_t)(2 * l) * 64 + b) * 2 + tt] = rpe;
  out_rpos[((size_t)(2 * l + 1) * 64 + b) * 2 + tt] = rpo;
  out_wpos[((size_t)(2 * l) * 64 + b) * 2 + tt] = wpe;
  out_wpos[((size_t)(2 * l + 1) * 64 + b) * 2 + tt] = wpo;
}

// ---------------- K5: tape scan — 1 barrier/step, ping-pong prefetch --------
__global__ __launch_bounds__(256) void k_tape(
    const float* values, const u16* wcoef, const u16* rcoef, const float* rw1arr,
    u16* readouts, float* out_tape) {
  const int bt = blockIdx.x;
  const int b = bt >> 1, t = bt & 1;
  const int tid = threadIdx.x;
  const int c = tid & 63;
  const int g = __builtin_amdgcn_readfirstlane(tid >> 6);
  __shared__ float lds_po[2][256];
  __shared__ float lds_pr[2][256];
  float tape[32];
#pragma unroll
  for (int j = 0; j < 32; ++j) tape[j] = 0.f;

  const unsigned* wcu = (const unsigned*)wcoef;
  const unsigned* rcu = (const unsigned*)rcoef;
  const size_t cbase = (size_t)bt * 64 + g * 16;
  const size_t vbase = (size_t)b * 128 + t * 64 + c;
  unsigned wA[16], rA[16], wB[16], rB[16];
  float rwA, rwB, vA, vB;
#pragma unroll
  for (int q = 0; q < 16; ++q) { wA[q] = wcu[cbase + q]; rA[q] = rcu[cbase + q]; }
  rwA = rw1arr[bt]; vA = values[vbase];
  {
    size_t nb = cbase + 8192;
#pragma unroll
    for (int q = 0; q < 16; ++q) { wB[q] = wcu[nb + q]; rB[q] = rcu[nb + q]; }
    rwB = rw1arr[128 + bt]; vB = values[8192 + vbase];
  }

#define TSTEP(CW, CR, CRW, CV, S)                                              \
  {                                                                            \
    const int s_ = (S);                                                        \
    float rwc = CRW, vcl = CV;                                                 \
    float wuf[32], ruf[32];                                                    \
    _Pragma("unroll") for (int q = 0; q < 16; ++q) {                           \
      wuf[2 * q] = __builtin_bit_cast(float, CW[q] << 16);                     \
      wuf[2 * q + 1] = __builtin_bit_cast(float, CW[q] & 0xffff0000u);         \
      ruf[2 * q] = __builtin_bit_cast(float, CR[q] << 16);                     \
      ruf[2 * q + 1] = __builtin_bit_cast(float, CR[q] & 0xffff0000u);         \
    }                                                                          \
    if (s_ + 2 < 256) {                                                        \
      size_t nb = cbase + (size_t)(s_ + 2) * 8192;                             \
      _Pragma("unroll") for (int q = 0; q < 16; ++q) {                         \
        CW[q] = wcu[nb + q]; CR[q] = rcu[nb + q]; }                            \
      CRW = rw1arr[(s_ + 2) * 128 + bt];                                       \
      CV = values[(size_t)(s_ + 2) * 8192 + vbase];                            \
    }                                                                          \
    float po = 0.f;                                                            \
    _Pragma("unroll") for (int j = 0; j < 32; ++j) po += tape[j] * wuf[j];     \
    lds_po[s_ & 1][(g << 6) + c] = po;                                         \
    __syncthreads();                                                           \
    if (g == 1 && s_ > 0) {                                                    \
      const float* pp = lds_pr[(s_ - 1) & 1];                                  \
      float ro = pp[c] + pp[64 + c] + pp[128 + c] + pp[192 + c];               \
      readouts[((size_t)(s_ - 1) * 64 + b) * 128 + t * 64 + c] = f2bf(ro);     \
    }                                                                          \
    const float* qq = lds_po[s_ & 1];                                          \
    float oldv = qq[c] + qq[64 + c] + qq[128 + c] + qq[192 + c];               \
    float dsc = rwc * (vcl - oldv);                                            \
    float pr = 0.f;                                                            \
    _Pragma("unroll") for (int j = 0; j < 32; ++j) {                           \
      tape[j] += wuf[j] * dsc;                                                 \
      pr += tape[j] * ruf[j];                                                  \
    }                                                                          \
    lds_pr[s_ & 1][(g << 6) + c] = pr;                                         \
  }

  for (int s = 0; s < 256; s += 2) {
    TSTEP(wA, rA, rwA, vA, s);
    TSTEP(wB, rB, rwB, vB, s + 1);
  }
#undef TSTEP
  __syncthreads();
  if (g == 1) {
    const float* pp = lds_pr[1];
    float ro = pp[c] + pp[64 + c] + pp[128 + c] + pp[192 + c];
    readouts[((size_t)255 * 64 + b) * 128 + t * 64 + c] = f2bf(ro);
  }
#pragma unroll
  for (int j = 0; j < 32; ++j) {
    int l = (g << 5) + j;
    out_tape[((size_t)(l * 64 + b) * 2 + t) * 64 + c] = tape[j];
  }
}

// ---------------------------------------------------------------------------
extern "C" void kernel_launch(void* const* d_in, const int* in_sizes, int n_in,
                              void* d_out, int out_size, void* d_ws, size_t ws_size,
                              hipStream_t stream) {
  const float* inputs = (const float*)d_in[0];
  const float* W_ih_f = (const float*)d_in[2];
  const float* W_hh_f = (const float*)d_in[3];
  const float* b_ih_f = (const float*)d_in[4];
  const float* b_hh_f = (const float*)d_in[5];
  const float* W_ih_r = (const float*)d_in[6];
  const float* W_hh_r = (const float*)d_in[7];
  const float* b_ih_r = (const float*)d_in[8];
  const float* b_hh_r = (const float*)d_in[9];
  const float* W_act  = (const float*)d_in[10];
  const float* b_act  = (const float*)d_in[11];
  const float* W_val  = (const float*)d_in[12];
  const float* b_val  = (const float*)d_in[13];
  const float* W_out  = (const float*)d_in[14];
  const float* b_out  = (const float*)d_in[15];

  char* ws = (char*)d_ws;
  u16* in_bf    = (u16*)(ws + 0);
  u16* wihf_bf  = (u16*)(ws + 4194304);
  u16* whhf_bf  = (u16*)(ws + 4259840);
  u16* wihr_bf  = (u16*)(ws + 4292608);
  u16* whhr_bf  = (u16*)(ws + 4358144);
  u16* wval_bf  = (u16*)(ws + 4390912);
  u16* wout_bf  = (u16*)(ws + 4423680);
  u16* wact_bf  = (u16*)(ws + 4456448);
  float* xf       = (float*)(ws + 4460544);
  float* xr       = (float*)(ws + 21237760);
  float* values   = (float*)(ws + 38014976);
  u16* hidden_bf  = (u16*)(ws + 46403584);
  float* actraw   = (float*)(ws + 50597888);
  float* act      = (float*)(ws + 52695040);   // ends 53743616
  // overlays (xf/xr dead after k_lstm):
  u16* wcoef    = (u16*)(ws + 4460544);
  u16* rcoef    = (u16*)(ws + 12849152);
  float* rw1arr = (float*)(ws + 21237760);
  u16* readouts = (u16*)(ws + 21368832);       // ends 25563136 < 38014976 OK

  float* out_outputs = (float*)d_out;
  float* out_tape = out_outputs + 2097152;
  float* out_rpos = out_outputs + 3145728;
  float* out_wpos = out_outputs + 3162112;

  ConvArgs ca;
  ca.src[0] = inputs; ca.dst[0] = in_bf;
  ca.src[1] = W_ih_f; ca.dst[1] = wihf_bf;
  ca.src[2] = W_hh_f; ca.dst[2] = whhf_bf;
  ca.src[3] = W_ih_r; ca.dst[3] = wihr_bf;
  ca.src[4] = W_hh_r; ca.dst[4] = whhr_bf;
  ca.src[5] = W_val;  ca.dst[5] = wval_bf;
  ca.src[6] = W_out;  ca.dst[6] = wout_bf;
  ca.src[7] = W_act;  ca.dst[7] = wact_bf;
  const int offs[9] = {0, 2097152, 2129920, 2146304, 2179072, 2195456,
                       2211840, 2228224, 2230272};
  for (int i = 0; i < 9; ++i) ca.off[i] = offs[i];

  hipLaunchKernelGGL(k_convert, dim3(4352), dim3(256), 0, stream, ca);
  hipLaunchKernelGGL(k_gemm_in, dim3(10240), dim3(256), 0, stream,
                     in_bf, wihf_bf, wihr_bf, wval_bf,
                     b_ih_f, b_hh_f, b_ih_r, b_hh_r, b_val, xf, xr, values);
  hipLaunchKernelGGL(k_lstm, dim3(8), dim3(256), 0, stream,
                     whhf_bf, whhr_bf, xf, xr, hidden_bf);
  hipLaunchKernelGGL(k_gemm_act, dim3(512), dim3(256), 0, stream,
                     hidden_bf, wact_bf, b_act, actraw);
  hipLaunchKernelGGL(k_actsm, dim3(128), dim3(256), 0, stream, actraw, act);
  hipLaunchKernelGGL(k_pos, dim3(128), dim3(64), 0, stream,
                     act, wcoef, rcoef, rw1arr, out_rpos, out_wpos);
  hipLaunchKernelGGL(k_tape, dim3(128), dim3(256), 0, stream,
                     values, wcoef, rcoef, rw1arr, readouts, out_tape);
  hipLaunchKernelGGL(k_gemm_out, dim3(2048), dim3(256), 0, stream,
                     readouts, wout_bf, b_out, out_outputs);
}